// Round 1
// baseline (465.704 us; speedup 1.0000x reference)
//
#include <hip/hip_runtime.h>
#include <cstdint>
#include <cstddef>

// Problem constants (from reference)
#define D_MODEL   1024
#define STATE_DIM 512
#define BATCH     4
#define SEQ_LEN   8192
#define M_TOTAL   (BATCH * SEQ_LEN)   // 32768

typedef unsigned short ushort_t;
typedef __attribute__((ext_vector_type(8))) __bf16 bf16x8;
typedef __attribute__((ext_vector_type(4))) float  f32x4;

// ---------- helpers ----------

__device__ inline ushort_t f2bf(float f) {
  union { float f; uint32_t u; } v; v.f = f;
  uint32_t u = v.u;
  uint32_t r = (u + 0x7FFFu + ((u >> 16) & 1u)) >> 16;  // RNE
  return (ushort_t)r;
}

// async global->LDS, 16B per lane. LDS dest = wave-uniform base + lane*16.
__device__ inline void llds16(const void* g, void* l) {
  __builtin_amdgcn_global_load_lds(
      (__attribute__((address_space(1))) void*)(void*)g,
      (__attribute__((address_space(3))) void*)l,
      16, 0, 0);
}

// ---------- fp32 -> bf16 conversion (vectorized) ----------

__global__ void convert_f32_bf16(const float* __restrict__ in,
                                 ushort_t* __restrict__ out, int n4) {
  int i = blockIdx.x * blockDim.x + threadIdx.x;
  if (i >= n4) return;
  const float4 v = ((const float4*)in)[i];
  ushort4 o;
  o.x = f2bf(v.x); o.y = f2bf(v.y); o.z = f2bf(v.z); o.w = f2bf(v.w);
  ((ushort4*)out)[i] = o;
}

// ---------- eigenvalues: lambda_j = (1 - i*w_j)/(1 + i*w_j), w = Im(FFT(a_full)) ----------
// lam layout: [0:512) re, [512:1024) im, [1024:1536) re(lam^128), [1536:2048) im(lam^128)

__global__ void eigen_kernel(const float* __restrict__ a_params,
                             float* __restrict__ lam) {
  __shared__ float af[STATE_DIM];
  const int k = threadIdx.x;  // 512 threads
  float v = 0.f;
  if (k >= 1 && k <= STATE_DIM / 2)      v = a_params[k - 1];
  else if (k > STATE_DIM / 2)            v = -a_params[STATE_DIM - k];
  af[k] = v;
  __syncthreads();
  // w_k = Im(sum_n af[n] * e^{-2*pi*i*k*n/512}) = -sum_n af[n]*sin(2*pi*k*n/512)
  // exact integer reduction of k*n mod 512 keeps sinf args in [0, 2*pi)
  float om = 0.f;
  const float c = 6.283185307179586f / 512.0f;
  for (int n = 1; n < STATE_DIM; ++n) {
    int p = (k * n) & 511;
    om -= af[n] * sinf(c * (float)p);
  }
  const float d  = 1.f / (1.f + om * om);
  const float lr = (1.f - om * om) * d;
  const float li = -2.f * om * d;           // |lambda| == 1 analytically
  // lambda^128 via double-precision angle (kills phase drift over 8192 steps)
  double th = atan2((double)li, (double)lr) * 128.0;
  lam[k]        = lr;
  lam[512 + k]  = li;
  lam[1024 + k] = (float)cos(th);
  lam[1536 + k] = (float)sin(th);
}

// ---------- bf16 MFMA GEMM, B^T layout: out[m][n] = sum_k A[m][k]*Bw[n][k] ----------
// 128x128 tile / block, 4 waves, each wave 64x64 as 4x4 of 16x16x32 MFMAs.

template <int KDIM, int NDIM, bool FUSE_SKIP>
__global__ __launch_bounds__(256, 2)
void gemm_bt(const ushort_t* __restrict__ A,    // M x KDIM  (bf16)
             const ushort_t* __restrict__ Bw,   // NDIM x KDIM (bf16)
             float* __restrict__ out,           // M x NDIM  (fp32)
             const float* __restrict__ skip_u,  // M x NDIM  (fp32) or null
             const float* __restrict__ Dvec) {  // NDIM or null
  __shared__ __align__(16) ushort_t smA[128 * 32];
  __shared__ __align__(16) ushort_t smB[128 * 32];
  const int tid    = threadIdx.x;
  const int wave   = tid >> 6, lane = tid & 63;
  const int lane16 = lane & 15, quad = lane >> 4;
  const int wm = (wave & 1) * 64, wn = (wave >> 1) * 64;
  const int row0 = blockIdx.x * 128;
  const int col0 = blockIdx.y * 128;

  f32x4 acc[4][4];
#pragma unroll
  for (int i = 0; i < 4; ++i)
#pragma unroll
    for (int j = 0; j < 4; ++j) {
      f32x4 z = {0.f, 0.f, 0.f, 0.f};
      acc[i][j] = z;
    }

  for (int k0 = 0; k0 < KDIM; k0 += 32) {
    // stage A/B tiles (128 rows x 32 cols bf16, row-major, 64B rows)
#pragma unroll
    for (int s = 0; s < 2; ++s) {
      const int c = s * 256 + tid;          // chunk index, 16B chunks
      const ushort_t* gA = A  + (size_t)(row0 + (c >> 2)) * KDIM + k0 + (c & 3) * 8;
      const ushort_t* gB = Bw + (size_t)(col0 + (c >> 2)) * KDIM + k0 + (c & 3) * 8;
      const int ldsoff = (s * 256 + wave * 64) * 16;  // wave-uniform byte base
      llds16(gA, (char*)smA + ldsoff);
      llds16(gB, (char*)smB + ldsoff);
    }
    __syncthreads();  // drains vmcnt(0): LDS staging complete

    bf16x8 af[4], bfr[4];
#pragma unroll
    for (int mi = 0; mi < 4; ++mi)
      af[mi] = *(const bf16x8*)(smA + (wm + mi * 16 + lane16) * 32 + quad * 8);
#pragma unroll
    for (int ni = 0; ni < 4; ++ni)
      bfr[ni] = *(const bf16x8*)(smB + (wn + ni * 16 + lane16) * 32 + quad * 8);
#pragma unroll
    for (int mi = 0; mi < 4; ++mi)
#pragma unroll
      for (int ni = 0; ni < 4; ++ni)
        acc[mi][ni] = __builtin_amdgcn_mfma_f32_16x16x32_bf16(
            af[mi], bfr[ni], acc[mi][ni], 0, 0, 0);
    __syncthreads();  // all waves done reading before next staging overwrites
  }

  // epilogue: C/D layout col=lane&15, row=quad*4+reg (verified m89/m91)
#pragma unroll
  for (int mi = 0; mi < 4; ++mi) {
#pragma unroll
    for (int ni = 0; ni < 4; ++ni) {
      const int row = row0 + wm + mi * 16 + quad * 4;
      const int col = col0 + wn + ni * 16 + lane16;
      float dv = 0.f;
      if (FUSE_SKIP) dv = Dvec[col];
#pragma unroll
      for (int r = 0; r < 4; ++r) {
        const size_t o = (size_t)(row + r) * NDIM + col;
        float val = acc[mi][ni][r];
        if (FUSE_SKIP) val = fmaf(dv, skip_u[o], val);
        out[o] = val;
      }
    }
  }
}

// ---------- chunked complex scan: h[t] = lam*h[t-1] + Bu[t], output Re(h) as bf16 ----------
// T=8192 split into 64 chunks of 128. Grid: BATCH*64 blocks x 512 threads (1 per channel).

#define NCHUNK 64
#define CLEN   128
#define SOFF   (BATCH * NCHUNK * STATE_DIM)  // 131072: im-plane offset in S/Hin

__global__ __launch_bounds__(512)
void scan_chunks(const float* __restrict__ Bu, const float* __restrict__ lam,
                 float* __restrict__ S) {
  const int j = threadIdx.x;
  const int c = blockIdx.x & (NCHUNK - 1);
  const int b = blockIdx.x >> 6;
  const float lr = lam[j], li = lam[512 + j];
  const float* p = Bu + ((size_t)(b * SEQ_LEN + c * CLEN)) * STATE_DIM + j;
  float hr = 0.f, hi = 0.f;
#pragma unroll 4
  for (int t = 0; t < CLEN; ++t) {
    const float x  = p[(size_t)t * STATE_DIM];
    const float nr = fmaf(lr, hr, fmaf(-li, hi, x));
    const float ni = fmaf(lr, hi, li * hr);
    hr = nr; hi = ni;
  }
  const size_t o = (size_t)(b * NCHUNK + c) * STATE_DIM + j;
  S[o] = hr; S[SOFF + o] = hi;
}

__global__ __launch_bounds__(512)
void scan_carry(const float* __restrict__ lam, const float* __restrict__ S,
                float* __restrict__ Hin) {
  const int idx = blockIdx.x * blockDim.x + threadIdx.x;  // 2048 = BATCH*512
  const int j = idx & 511, b = idx >> 9;
  const float pr = lam[1024 + j], pi = lam[1536 + j];  // lambda^128
  float cr = 0.f, ci = 0.f;
  for (int c = 0; c < NCHUNK; ++c) {
    const size_t o = (size_t)(b * NCHUNK + c) * STATE_DIM + j;
    Hin[o] = cr; Hin[SOFF + o] = ci;
    const float sr = S[o], si = S[SOFF + o];
    const float nr = fmaf(pr, cr, fmaf(-pi, ci, sr));
    const float ni = fmaf(pr, ci, fmaf(pi, cr, si));
    cr = nr; ci = ni;
  }
}

__global__ __launch_bounds__(512)
void scan_final(const float* __restrict__ Bu, const float* __restrict__ lam,
                const float* __restrict__ Hin, ushort_t* __restrict__ h) {
  const int j = threadIdx.x;
  const int c = blockIdx.x & (NCHUNK - 1);
  const int b = blockIdx.x >> 6;
  const float lr = lam[j], li = lam[512 + j];
  const size_t so = (size_t)(b * NCHUNK + c) * STATE_DIM + j;
  float hr = Hin[so], hi = Hin[SOFF + so];
  const size_t base = ((size_t)(b * SEQ_LEN + c * CLEN)) * STATE_DIM + j;
#pragma unroll 4
  for (int t = 0; t < CLEN; ++t) {
    const float x  = Bu[base + (size_t)t * STATE_DIM];
    const float nr = fmaf(lr, hr, fmaf(-li, hi, x));
    const float ni = fmaf(lr, hi, li * hr);
    hr = nr; hi = ni;
    h[base + (size_t)t * STATE_DIM] = f2bf(hr);
  }
}

// ---------- launch ----------

extern "C" void kernel_launch(void* const* d_in, const int* in_sizes, int n_in,
                              void* d_out, int out_size, void* d_ws, size_t ws_size,
                              hipStream_t stream) {
  const float* u  = (const float*)d_in[0];  // (4, 8192, 1024)
  const float* ap = (const float*)d_in[1];  // (256,)
  const float* Bw = (const float*)d_in[2];  // (512, 1024)
  const float* Cw = (const float*)d_in[3];  // (1024, 512)
  const float* Dv = (const float*)d_in[4];  // (1024,)
  float* y = (float*)d_out;                 // (4, 8192, 1024)

  char* ws = (char*)d_ws;
  // workspace layout (bytes), total ~164 MB
  ushort_t* ub  = (ushort_t*)(ws + 0);            // u bf16:   67,108,864
  ushort_t* bwb = (ushort_t*)(ws + 67108864);     // B_w bf16:  1,048,576
  ushort_t* cwb = (ushort_t*)(ws + 68157440);     // C_w bf16:  1,048,576
  float*    lam = (float*)   (ws + 69206016);     // lambdas:       8,192
  float*    Bu  = (float*)   (ws + 69214208);     // Bu fp32:  67,108,864
  ushort_t* hb  = (ushort_t*)(ws + 136323072);    // h bf16:   33,554,432
  float*    S   = (float*)   (ws + 169877504);    // chunk states: 1,048,576
  float*    Hin = (float*)   (ws + 170926080);    // carries:      1,048,576

  convert_f32_bf16<<<32768, 256, 0, stream>>>(u,  ub,  (M_TOTAL * D_MODEL) / 4);
  convert_f32_bf16<<<512,   256, 0, stream>>>(Bw, bwb, (STATE_DIM * D_MODEL) / 4);
  convert_f32_bf16<<<512,   256, 0, stream>>>(Cw, cwb, (D_MODEL * STATE_DIM) / 4);
  eigen_kernel<<<1, 512, 0, stream>>>(ap, lam);

  // Bu = u @ B_w^T : M=32768, N=512, K=1024
  gemm_bt<D_MODEL, STATE_DIM, false>
      <<<dim3(M_TOTAL / 128, STATE_DIM / 128), 256, 0, stream>>>(
          ub, bwb, Bu, nullptr, nullptr);

  scan_chunks<<<BATCH * NCHUNK, 512, 0, stream>>>(Bu, lam, S);
  scan_carry<<<BATCH, 512, 0, stream>>>(lam, S, Hin);
  scan_final<<<BATCH * NCHUNK, 512, 0, stream>>>(Bu, lam, Hin, hb);

  // y = h @ C_w^T + D*u : M=32768, N=1024, K=512
  gemm_bt<STATE_DIM, D_MODEL, true>
      <<<dim3(M_TOTAL / 128, D_MODEL / 128), 256, 0, stream>>>(
          hb, cwb, y, u, Dv);
}

// Round 2
// 392.536 us; speedup vs baseline: 1.1864x; 1.1864x over previous
//
#include <hip/hip_runtime.h>
#include <cstdint>
#include <cstddef>

// Problem constants (from reference)
#define D_MODEL   1024
#define STATE_DIM 512
#define BATCH     4
#define SEQ_LEN   8192
#define M_TOTAL   (BATCH * SEQ_LEN)   // 32768

typedef unsigned short ushort_t;
typedef __attribute__((ext_vector_type(8))) __bf16 bf16x8;
typedef __attribute__((ext_vector_type(4))) float  f32x4;

// ---------- helpers ----------

__device__ inline ushort_t f2bf(float f) {
  union { float f; uint32_t u; } v; v.f = f;
  uint32_t u = v.u;
  uint32_t r = (u + 0x7FFFu + ((u >> 16) & 1u)) >> 16;  // RNE
  return (ushort_t)r;
}

__device__ inline float bf2f(ushort_t b) {
  union { uint32_t u; float f; } v; v.u = ((uint32_t)b) << 16;
  return v.f;
}

// async global->LDS, 16B per lane. LDS dest = wave-uniform base + lane*16.
__device__ inline void llds16(const void* g, void* l) {
  __builtin_amdgcn_global_load_lds(
      (__attribute__((address_space(1))) void*)(void*)g,
      (__attribute__((address_space(3))) void*)l,
      16, 0, 0);
}

// ---------- fp32 -> bf16 conversion (vectorized) ----------

__global__ void convert_f32_bf16(const float* __restrict__ in,
                                 ushort_t* __restrict__ out, int n4) {
  int i = blockIdx.x * blockDim.x + threadIdx.x;
  if (i >= n4) return;
  const float4 v = ((const float4*)in)[i];
  ushort4 o;
  o.x = f2bf(v.x); o.y = f2bf(v.y); o.z = f2bf(v.z); o.w = f2bf(v.w);
  ((ushort4*)out)[i] = o;
}

// ---------- eigenvalues ----------
// lambda_j = (1 - i*w_j)/(1 + i*w_j), w = Im(FFT(a_full)).
// lam layout: [0:512) re, [512:1024) im, [1024:1536) re(lam^128), [1536:2048) im(lam^128)
// 512 blocks (one per k) x 64 lanes; shuffle-reduce the 512-term DFT sum.

__global__ __launch_bounds__(64)
void eigen_kernel(const float* __restrict__ a_params, float* __restrict__ lam) {
  const int k = blockIdx.x;
  const int l = threadIdx.x;
  const float c = 6.283185307179586f / 512.0f;
  float om = 0.f;
#pragma unroll
  for (int s = 0; s < 8; ++s) {
    const int n = s * 64 + l;
    float v = 0.f;
    if (n >= 1 && n <= STATE_DIM / 2)      v = a_params[n - 1];
    else if (n > STATE_DIM / 2)            v = -a_params[STATE_DIM - n];
    const int p = (k * n) & 511;            // exact integer phase reduction
    om -= v * sinf(c * (float)p);
  }
#pragma unroll
  for (int off = 32; off; off >>= 1) om += __shfl_down(om, off);
  if (l == 0) {
    const float d  = 1.f / (1.f + om * om);
    const float lr = (1.f - om * om) * d;
    const float li = -2.f * om * d;         // |lambda| == 1 analytically
    double th = atan2((double)li, (double)lr) * 128.0;
    lam[k]        = lr;
    lam[512 + k]  = li;
    lam[1024 + k] = (float)cos(th);
    lam[1536 + k] = (float)sin(th);
  }
}

// ---------- bf16 MFMA GEMM, B^T layout: out[m][n] = sum_k A[m][k]*Bw[n][k] ----------
// 128x128 tile / block, 4 waves, each wave 64x64 as 4x4 of 16x16x32 MFMAs.
// LDS tiles use an XOR swizzle: logical k-chunk c (16B) of row r is stored at
// physical chunk c ^ ((r>>1)&3), spreading ds_read_b128 fragment reads across
// all 8 bank-groups (conflict-free) while keeping global_load_lds staging
// lane-contiguous (source-address permutation within the same 64B line).

template <int KDIM, int NDIM, bool OUT_BF16, bool FUSE_SKIP>
__global__ __launch_bounds__(256, 4)
void gemm_bt(const ushort_t* __restrict__ A,       // M x KDIM  (bf16)
             const ushort_t* __restrict__ Bw,      // NDIM x KDIM (bf16)
             void* __restrict__ outv,              // M x NDIM
             const ushort_t* __restrict__ skip_b,  // M x NDIM (bf16) or null
             const float* __restrict__ Dvec) {     // NDIM or null
  __shared__ __align__(16) ushort_t smA[128 * 32];
  __shared__ __align__(16) ushort_t smB[128 * 32];
  const int tid    = threadIdx.x;
  const int wave   = tid >> 6, lane = tid & 63;
  const int lane16 = lane & 15, quad = lane >> 4;
  const int wm = (wave & 1) * 64, wn = (wave >> 1) * 64;
  const int row0 = blockIdx.x * 128;
  const int col0 = blockIdx.y * 128;

  f32x4 acc[4][4];
#pragma unroll
  for (int i = 0; i < 4; ++i)
#pragma unroll
    for (int j = 0; j < 4; ++j) {
      f32x4 z = {0.f, 0.f, 0.f, 0.f};
      acc[i][j] = z;
    }

  // per-lane swizzled source chunk for staging (constant across K-iters)
  const int s_r0 = tid >> 2;                              // rows 0..63
  const int s_c0 = (tid & 3) ^ ((s_r0 >> 1) & 3);
  const int s_r1 = (256 + tid) >> 2;                      // rows 64..127
  const int s_c1 = (tid & 3) ^ ((s_r1 >> 1) & 3);

  for (int k0 = 0; k0 < KDIM; k0 += 32) {
    {
      const ushort_t* gA0 = A  + (size_t)(row0 + s_r0) * KDIM + k0 + s_c0 * 8;
      const ushort_t* gB0 = Bw + (size_t)(col0 + s_r0) * KDIM + k0 + s_c0 * 8;
      const ushort_t* gA1 = A  + (size_t)(row0 + s_r1) * KDIM + k0 + s_c1 * 8;
      const ushort_t* gB1 = Bw + (size_t)(col0 + s_r1) * KDIM + k0 + s_c1 * 8;
      const int o0 = (wave * 64) * 16;          // wave-uniform byte base
      const int o1 = (256 + wave * 64) * 16;
      llds16(gA0, (char*)smA + o0);
      llds16(gB0, (char*)smB + o0);
      llds16(gA1, (char*)smA + o1);
      llds16(gB1, (char*)smB + o1);
    }
    __syncthreads();  // drains vmcnt(0): LDS staging complete

    bf16x8 af[4], bfr[4];
#pragma unroll
    for (int mi = 0; mi < 4; ++mi) {
      const int m = wm + mi * 16 + lane16;
      const int pc = quad ^ ((m >> 1) & 3);
      af[mi] = *(const bf16x8*)(smA + (m * 4 + pc) * 8);
    }
#pragma unroll
    for (int ni = 0; ni < 4; ++ni) {
      const int n = wn + ni * 16 + lane16;
      const int pc = quad ^ ((n >> 1) & 3);
      bfr[ni] = *(const bf16x8*)(smB + (n * 4 + pc) * 8);
    }
#pragma unroll
    for (int mi = 0; mi < 4; ++mi)
#pragma unroll
      for (int ni = 0; ni < 4; ++ni)
        acc[mi][ni] = __builtin_amdgcn_mfma_f32_16x16x32_bf16(
            af[mi], bfr[ni], acc[mi][ni], 0, 0, 0);
    __syncthreads();  // all waves done reading before next staging overwrites
  }

  // epilogue: C/D layout col=lane&15, row=quad*4+reg (verified m89/m91)
#pragma unroll
  for (int mi = 0; mi < 4; ++mi) {
#pragma unroll
    for (int ni = 0; ni < 4; ++ni) {
      const int row = row0 + wm + mi * 16 + quad * 4;
      const int col = col0 + wn + ni * 16 + lane16;
      float dv = 0.f;
      if (FUSE_SKIP) dv = Dvec[col];
#pragma unroll
      for (int r = 0; r < 4; ++r) {
        const size_t o = (size_t)(row + r) * NDIM + col;
        float val = acc[mi][ni][r];
        if (FUSE_SKIP) val = fmaf(dv, bf2f(skip_b[o]), val);
        if (OUT_BF16) ((ushort_t*)outv)[o] = f2bf(val);
        else          ((float*)outv)[o] = val;
      }
    }
  }
}

// ---------- chunked complex scan: h[t] = lam*h[t-1] + Bu[t], output Re(h) as bf16 ----------
// T=8192 split into 64 chunks of 128. Grid: BATCH*64 blocks x 512 threads (1 per channel).

#define NCHUNK 64
#define CLEN   128
#define SOFF   (BATCH * NCHUNK * STATE_DIM)  // 131072: im-plane offset in S/Hin

__global__ __launch_bounds__(512)
void scan_chunks(const ushort_t* __restrict__ Bu, const float* __restrict__ lam,
                 float* __restrict__ S) {
  const int j = threadIdx.x;
  const int c = blockIdx.x & (NCHUNK - 1);
  const int b = blockIdx.x >> 6;
  const float lr = lam[j], li = lam[512 + j];
  const ushort_t* p = Bu + ((size_t)(b * SEQ_LEN + c * CLEN)) * STATE_DIM + j;
  float hr = 0.f, hi = 0.f;
#pragma unroll 4
  for (int t = 0; t < CLEN; ++t) {
    const float x  = bf2f(p[(size_t)t * STATE_DIM]);
    const float nr = fmaf(lr, hr, fmaf(-li, hi, x));
    const float ni = fmaf(lr, hi, li * hr);
    hr = nr; hi = ni;
  }
  const size_t o = (size_t)(b * NCHUNK + c) * STATE_DIM + j;
  S[o] = hr; S[SOFF + o] = hi;
}

__global__ __launch_bounds__(512)
void scan_carry(const float* __restrict__ lam, const float* __restrict__ S,
                float* __restrict__ Hin) {
  const int idx = blockIdx.x * blockDim.x + threadIdx.x;  // 2048 = BATCH*512
  const int j = idx & 511, b = idx >> 9;
  const float pr = lam[1024 + j], pi = lam[1536 + j];  // lambda^128
  float cr = 0.f, ci = 0.f;
  for (int c = 0; c < NCHUNK; ++c) {
    const size_t o = (size_t)(b * NCHUNK + c) * STATE_DIM + j;
    Hin[o] = cr; Hin[SOFF + o] = ci;
    const float sr = S[o], si = S[SOFF + o];
    const float nr = fmaf(pr, cr, fmaf(-pi, ci, sr));
    const float ni = fmaf(pr, ci, fmaf(pi, cr, si));
    cr = nr; ci = ni;
  }
}

__global__ __launch_bounds__(512)
void scan_final(const ushort_t* __restrict__ Bu, const float* __restrict__ lam,
                const float* __restrict__ Hin, ushort_t* __restrict__ h) {
  const int j = threadIdx.x;
  const int c = blockIdx.x & (NCHUNK - 1);
  const int b = blockIdx.x >> 6;
  const float lr = lam[j], li = lam[512 + j];
  const size_t so = (size_t)(b * NCHUNK + c) * STATE_DIM + j;
  float hr = Hin[so], hi = Hin[SOFF + so];
  const size_t base = ((size_t)(b * SEQ_LEN + c * CLEN)) * STATE_DIM + j;
#pragma unroll 4
  for (int t = 0; t < CLEN; ++t) {
    const float x  = bf2f(Bu[base + (size_t)t * STATE_DIM]);
    const float nr = fmaf(lr, hr, fmaf(-li, hi, x));
    const float ni = fmaf(lr, hi, li * hr);
    hr = nr; hi = ni;
    h[base + (size_t)t * STATE_DIM] = f2bf(hr);
  }
}

// ---------- launch ----------

extern "C" void kernel_launch(void* const* d_in, const int* in_sizes, int n_in,
                              void* d_out, int out_size, void* d_ws, size_t ws_size,
                              hipStream_t stream) {
  const float* u  = (const float*)d_in[0];  // (4, 8192, 1024)
  const float* ap = (const float*)d_in[1];  // (256,)
  const float* Bw = (const float*)d_in[2];  // (512, 1024)
  const float* Cw = (const float*)d_in[3];  // (1024, 512)
  const float* Dv = (const float*)d_in[4];  // (1024,)
  float* y = (float*)d_out;                 // (4, 8192, 1024)

  char* ws = (char*)d_ws;
  // workspace layout (bytes), total ~138.4 MB
  ushort_t* ub  = (ushort_t*)(ws + 0);            // u bf16:    67,108,864
  ushort_t* bwb = (ushort_t*)(ws + 67108864);     // B_w bf16:   1,048,576
  ushort_t* cwb = (ushort_t*)(ws + 68157440);     // C_w bf16:   1,048,576
  float*    lam = (float*)   (ws + 69206016);     // lambdas:        8,192
  ushort_t* Bu  = (ushort_t*)(ws + 69214208);     // Bu bf16:   33,554,432
  ushort_t* hb  = (ushort_t*)(ws + 102768640);    // h bf16:    33,554,432
  float*    S   = (float*)   (ws + 136323072);    // chunk states: 1,048,576
  float*    Hin = (float*)   (ws + 137371648);    // carries:      1,048,576

  convert_f32_bf16<<<32768, 256, 0, stream>>>(u,  ub,  (M_TOTAL * D_MODEL) / 4);
  convert_f32_bf16<<<512,   256, 0, stream>>>(Bw, bwb, (STATE_DIM * D_MODEL) / 4);
  convert_f32_bf16<<<512,   256, 0, stream>>>(Cw, cwb, (D_MODEL * STATE_DIM) / 4);
  eigen_kernel<<<512, 64, 0, stream>>>(ap, lam);

  // Bu = u @ B_w^T : M=32768, N=512, K=1024  (bf16 out)
  gemm_bt<D_MODEL, STATE_DIM, true, false>
      <<<dim3(M_TOTAL / 128, STATE_DIM / 128), 256, 0, stream>>>(
          ub, bwb, Bu, nullptr, nullptr);

  scan_chunks<<<BATCH * NCHUNK, 512, 0, stream>>>(Bu, lam, S);
  scan_carry<<<BATCH, 512, 0, stream>>>(lam, S, Hin);
  scan_final<<<BATCH * NCHUNK, 512, 0, stream>>>(Bu, lam, Hin, hb);

  // y = h @ C_w^T + D*u : M=32768, N=1024, K=512  (fp32 out, bf16 skip)
  gemm_bt<STATE_DIM, D_MODEL, false, true>
      <<<dim3(M_TOTAL / 128, D_MODEL / 128), 256, 0, stream>>>(
          hb, cwb, y, ub, Dv);
}

// Round 3
// 374.561 us; speedup vs baseline: 1.2433x; 1.0480x over previous
//
#include <hip/hip_runtime.h>
#include <cstdint>
#include <cstddef>

// Problem constants (from reference)
#define D_MODEL   1024
#define STATE_DIM 512
#define BATCH     4
#define SEQ_LEN   8192
#define M_TOTAL   (BATCH * SEQ_LEN)   // 32768

typedef unsigned short ushort_t;
typedef __attribute__((ext_vector_type(8))) __bf16 bf16x8;
typedef __attribute__((ext_vector_type(4))) float  f32x4;

// ---------- helpers ----------

__device__ inline ushort_t f2bf(float f) {
  union { float f; uint32_t u; } v; v.f = f;
  uint32_t u = v.u;
  uint32_t r = (u + 0x7FFFu + ((u >> 16) & 1u)) >> 16;  // RNE
  return (ushort_t)r;
}

__device__ inline float bf2f(ushort_t b) {
  union { uint32_t u; float f; } v; v.u = ((uint32_t)b) << 16;
  return v.f;
}

// async global->LDS, 16B per lane. LDS dest = wave-uniform base + lane*16.
__device__ inline void llds16(const void* g, void* l) {
  __builtin_amdgcn_global_load_lds(
      (__attribute__((address_space(1))) void*)(void*)g,
      (__attribute__((address_space(3))) void*)l,
      16, 0, 0);
}

// ---------- fp32 -> bf16 conversion (vectorized) ----------

__global__ void convert_f32_bf16(const float* __restrict__ in,
                                 ushort_t* __restrict__ out, int n4) {
  int i = blockIdx.x * blockDim.x + threadIdx.x;
  if (i >= n4) return;
  const float4 v = ((const float4*)in)[i];
  ushort4 o;
  o.x = f2bf(v.x); o.y = f2bf(v.y); o.z = f2bf(v.z); o.w = f2bf(v.w);
  ((ushort4*)out)[i] = o;
}

// ---------- eigenvalues ----------
// lambda_j = (1 - i*w_j)/(1 + i*w_j), w = Im(FFT(a_full)).
// lam layout: [0:512) re, [512:1024) im, [1024:1536) re(lam^CLEN), [1536:2048) im(lam^CLEN)

#define NCHUNK 128
#define CLEN   64
#define SOFF   (BATCH * NCHUNK * STATE_DIM)  // 262144: im-plane offset in S/Hin

__global__ __launch_bounds__(64)
void eigen_kernel(const float* __restrict__ a_params, float* __restrict__ lam) {
  const int k = blockIdx.x;
  const int l = threadIdx.x;
  const float c = 6.283185307179586f / 512.0f;
  float om = 0.f;
#pragma unroll
  for (int s = 0; s < 8; ++s) {
    const int n = s * 64 + l;
    float v = 0.f;
    if (n >= 1 && n <= STATE_DIM / 2)      v = a_params[n - 1];
    else if (n > STATE_DIM / 2)            v = -a_params[STATE_DIM - n];
    const int p = (k * n) & 511;            // exact integer phase reduction
    om -= v * sinf(c * (float)p);
  }
#pragma unroll
  for (int off = 32; off; off >>= 1) om += __shfl_down(om, off);
  if (l == 0) {
    const float d  = 1.f / (1.f + om * om);
    const float lr = (1.f - om * om) * d;
    const float li = -2.f * om * d;         // |lambda| == 1 analytically
    double th = atan2((double)li, (double)lr) * (double)CLEN;
    lam[k]        = lr;
    lam[512 + k]  = li;
    lam[1024 + k] = (float)cos(th);
    lam[1536 + k] = (float)sin(th);
  }
}

// ---------- bf16 MFMA GEMM, B^T layout: out[m][n] = sum_k A[m][k]*Bw[n][k] ----------
// 128x128 tile / block, 4 waves, each wave 64x64 as 4x4 of 16x16x32 MFMAs.
// Double-buffered LDS: stage tile k+1 (async global_load_lds) BEFORE computing
// tile k, single barrier per iter — the vmcnt(0) drain at the barrier lands
// after compute, so prefetch latency overlaps MFMA instead of serializing.
// XOR swizzle (chunk c of row r at c ^ ((r>>1)&3)) keeps fragment ds_read_b128
// conflict-free while staging stays lane-contiguous.

template <int KDIM, int NDIM, bool OUT_BF16, bool FUSE_SKIP>
__global__ __launch_bounds__(256, 4)
void gemm_bt(const ushort_t* __restrict__ A,       // M x KDIM  (bf16)
             const ushort_t* __restrict__ Bw,      // NDIM x KDIM (bf16)
             void* __restrict__ outv,              // M x NDIM
             const ushort_t* __restrict__ skip_b,  // M x NDIM (bf16) or null
             const float* __restrict__ Dvec) {     // NDIM or null
  __shared__ __align__(16) ushort_t smA[2 * 128 * 32];
  __shared__ __align__(16) ushort_t smB[2 * 128 * 32];
  const int tid    = threadIdx.x;
  const int wave   = tid >> 6, lane = tid & 63;
  const int lane16 = lane & 15, quad = lane >> 4;
  const int wm = (wave & 1) * 64, wn = (wave >> 1) * 64;
  const int row0 = blockIdx.x * 128;
  const int col0 = blockIdx.y * 128;

  f32x4 acc[4][4];
#pragma unroll
  for (int i = 0; i < 4; ++i)
#pragma unroll
    for (int j = 0; j < 4; ++j) {
      f32x4 z = {0.f, 0.f, 0.f, 0.f};
      acc[i][j] = z;
    }

  // per-lane swizzled source chunk for staging (constant across K-iters)
  const int s_r0 = tid >> 2;                              // rows 0..63
  const int s_c0 = (tid & 3) ^ ((s_r0 >> 1) & 3);
  const int s_r1 = (256 + tid) >> 2;                      // rows 64..127
  const int s_c1 = (tid & 3) ^ ((s_r1 >> 1) & 3);
  const int o0 = (wave * 64) * 16;                        // wave-uniform bases
  const int o1 = (256 + wave * 64) * 16;

  const ushort_t* gA0 = A  + (size_t)(row0 + s_r0) * KDIM + s_c0 * 8;
  const ushort_t* gB0 = Bw + (size_t)(col0 + s_r0) * KDIM + s_c0 * 8;
  const ushort_t* gA1 = A  + (size_t)(row0 + s_r1) * KDIM + s_c1 * 8;
  const ushort_t* gB1 = Bw + (size_t)(col0 + s_r1) * KDIM + s_c1 * 8;

#define STAGE(k0, buf)                                                   \
  do {                                                                   \
    char* bA = (char*)(smA + (buf) * (128 * 32));                        \
    char* bB = (char*)(smB + (buf) * (128 * 32));                        \
    llds16(gA0 + (k0), bA + o0);                                         \
    llds16(gB0 + (k0), bB + o0);                                         \
    llds16(gA1 + (k0), bA + o1);                                         \
    llds16(gB1 + (k0), bB + o1);                                         \
  } while (0)

  STAGE(0, 0);
  __syncthreads();  // vmcnt(0) drain: first tile resident

  constexpr int NIT = KDIM / 32;
  int cur = 0;
#pragma unroll 2
  for (int it = 0; it < NIT; ++it) {
    if (it + 1 < NIT) STAGE((it + 1) * 32, cur ^ 1);  // async prefetch

    const ushort_t* sA = smA + cur * (128 * 32);
    const ushort_t* sB = smB + cur * (128 * 32);
    bf16x8 af[4], bfr[4];
#pragma unroll
    for (int mi = 0; mi < 4; ++mi) {
      const int m = wm + mi * 16 + lane16;
      const int pc = quad ^ ((m >> 1) & 3);
      af[mi] = *(const bf16x8*)(sA + (m * 4 + pc) * 8);
    }
#pragma unroll
    for (int ni = 0; ni < 4; ++ni) {
      const int n = wn + ni * 16 + lane16;
      const int pc = quad ^ ((n >> 1) & 3);
      bfr[ni] = *(const bf16x8*)(sB + (n * 4 + pc) * 8);
    }
#pragma unroll
    for (int mi = 0; mi < 4; ++mi)
#pragma unroll
      for (int ni = 0; ni < 4; ++ni)
        acc[mi][ni] = __builtin_amdgcn_mfma_f32_16x16x32_bf16(
            af[mi], bfr[ni], acc[mi][ni], 0, 0, 0);

    __syncthreads();  // prefetch resident; all waves done reading cur
    cur ^= 1;
  }
#undef STAGE

  // epilogue: C/D layout col=lane&15, row=quad*4+reg (verified m89/m91)
#pragma unroll
  for (int mi = 0; mi < 4; ++mi) {
#pragma unroll
    for (int ni = 0; ni < 4; ++ni) {
      const int row = row0 + wm + mi * 16 + quad * 4;
      const int col = col0 + wn + ni * 16 + lane16;
      float dv = 0.f;
      if (FUSE_SKIP) dv = Dvec[col];
#pragma unroll
      for (int r = 0; r < 4; ++r) {
        const size_t o = (size_t)(row + r) * NDIM + col;
        float val = acc[mi][ni][r];
        if (FUSE_SKIP) val = fmaf(dv, bf2f(skip_b[o]), val);
        if (OUT_BF16) ((ushort_t*)outv)[o] = f2bf(val);
        else          ((float*)outv)[o] = val;
      }
    }
  }
}

// ---------- chunked complex scan: h[t] = lam*h[t-1] + Bu[t], output Re(h) as bf16 ----------
// T=8192 split into 128 chunks of 64. Grid: BATCH*NCHUNK blocks x 128 threads,
// each thread owns 4 adjacent channels (ushort4 loads = 512B/wave, 4-way ILP).

__global__ __launch_bounds__(128)
void scan_chunks(const ushort_t* __restrict__ Bu, const float* __restrict__ lam,
                 float* __restrict__ S) {
  const int j = threadIdx.x * 4;                 // first of 4 channels
  const int c = blockIdx.x & (NCHUNK - 1);
  const int b = blockIdx.x >> 7;
  float lr[4], li[4], hr[4] = {0,0,0,0}, hi[4] = {0,0,0,0};
#pragma unroll
  for (int q = 0; q < 4; ++q) { lr[q] = lam[j + q]; li[q] = lam[512 + j + q]; }
  const ushort_t* p = Bu + ((size_t)(b * SEQ_LEN + c * CLEN)) * STATE_DIM + j;
#pragma unroll 4
  for (int t = 0; t < CLEN; ++t) {
    const ushort4 x4 = *(const ushort4*)(p + (size_t)t * STATE_DIM);
    const float x[4] = {bf2f(x4.x), bf2f(x4.y), bf2f(x4.z), bf2f(x4.w)};
#pragma unroll
    for (int q = 0; q < 4; ++q) {
      const float nr = fmaf(lr[q], hr[q], fmaf(-li[q], hi[q], x[q]));
      const float ni = fmaf(lr[q], hi[q], li[q] * hr[q]);
      hr[q] = nr; hi[q] = ni;
    }
  }
  const size_t o = (size_t)(b * NCHUNK + c) * STATE_DIM + j;
#pragma unroll
  for (int q = 0; q < 4; ++q) { S[o + q] = hr[q]; S[SOFF + o + q] = hi[q]; }
}

__global__ __launch_bounds__(512)
void scan_carry(const float* __restrict__ lam, const float* __restrict__ S,
                float* __restrict__ Hin) {
  const int idx = blockIdx.x * blockDim.x + threadIdx.x;  // 2048 = BATCH*512
  const int j = idx & 511, b = idx >> 9;
  const float pr = lam[1024 + j], pi = lam[1536 + j];  // lambda^CLEN
  float cr = 0.f, ci = 0.f;
  for (int c = 0; c < NCHUNK; ++c) {
    const size_t o = (size_t)(b * NCHUNK + c) * STATE_DIM + j;
    Hin[o] = cr; Hin[SOFF + o] = ci;
    const float sr = S[o], si = S[SOFF + o];
    const float nr = fmaf(pr, cr, fmaf(-pi, ci, sr));
    const float ni = fmaf(pr, ci, fmaf(pi, cr, si));
    cr = nr; ci = ni;
  }
}

__global__ __launch_bounds__(128)
void scan_final(const ushort_t* __restrict__ Bu, const float* __restrict__ lam,
                const float* __restrict__ Hin, ushort_t* __restrict__ h) {
  const int j = threadIdx.x * 4;
  const int c = blockIdx.x & (NCHUNK - 1);
  const int b = blockIdx.x >> 7;
  float lr[4], li[4], hr[4], hi[4];
#pragma unroll
  for (int q = 0; q < 4; ++q) { lr[q] = lam[j + q]; li[q] = lam[512 + j + q]; }
  const size_t so = (size_t)(b * NCHUNK + c) * STATE_DIM + j;
#pragma unroll
  for (int q = 0; q < 4; ++q) { hr[q] = Hin[so + q]; hi[q] = Hin[SOFF + so + q]; }
  const size_t base = ((size_t)(b * SEQ_LEN + c * CLEN)) * STATE_DIM + j;
#pragma unroll 4
  for (int t = 0; t < CLEN; ++t) {
    const ushort4 x4 = *(const ushort4*)(Bu + base + (size_t)t * STATE_DIM);
    const float x[4] = {bf2f(x4.x), bf2f(x4.y), bf2f(x4.z), bf2f(x4.w)};
    ushort4 o4;
#pragma unroll
    for (int q = 0; q < 4; ++q) {
      const float nr = fmaf(lr[q], hr[q], fmaf(-li[q], hi[q], x[q]));
      const float ni = fmaf(lr[q], hi[q], li[q] * hr[q]);
      hr[q] = nr; hi[q] = ni;
    }
    o4.x = f2bf(hr[0]); o4.y = f2bf(hr[1]); o4.z = f2bf(hr[2]); o4.w = f2bf(hr[3]);
    *(ushort4*)(h + base + (size_t)t * STATE_DIM) = o4;
  }
}

// ---------- launch ----------

extern "C" void kernel_launch(void* const* d_in, const int* in_sizes, int n_in,
                              void* d_out, int out_size, void* d_ws, size_t ws_size,
                              hipStream_t stream) {
  const float* u  = (const float*)d_in[0];  // (4, 8192, 1024)
  const float* ap = (const float*)d_in[1];  // (256,)
  const float* Bw = (const float*)d_in[2];  // (512, 1024)
  const float* Cw = (const float*)d_in[3];  // (1024, 512)
  const float* Dv = (const float*)d_in[4];  // (1024,)
  float* y = (float*)d_out;                 // (4, 8192, 1024)

  char* ws = (char*)d_ws;
  // workspace layout (bytes), total ~140.5 MB
  ushort_t* ub  = (ushort_t*)(ws + 0);            // u bf16:    67,108,864
  ushort_t* bwb = (ushort_t*)(ws + 67108864);     // B_w bf16:   1,048,576
  ushort_t* cwb = (ushort_t*)(ws + 68157440);     // C_w bf16:   1,048,576
  float*    lam = (float*)   (ws + 69206016);     // lambdas:        8,192
  ushort_t* Bu  = (ushort_t*)(ws + 69214208);     // Bu bf16:   33,554,432
  ushort_t* hb  = (ushort_t*)(ws + 102768640);    // h bf16:    33,554,432
  float*    S   = (float*)   (ws + 136323072);    // chunk states: 2,097,152
  float*    Hin = (float*)   (ws + 138420224);    // carries:      2,097,152

  convert_f32_bf16<<<32768, 256, 0, stream>>>(u,  ub,  (M_TOTAL * D_MODEL) / 4);
  convert_f32_bf16<<<512,   256, 0, stream>>>(Bw, bwb, (STATE_DIM * D_MODEL) / 4);
  convert_f32_bf16<<<512,   256, 0, stream>>>(Cw, cwb, (D_MODEL * STATE_DIM) / 4);
  eigen_kernel<<<512, 64, 0, stream>>>(ap, lam);

  // Bu = u @ B_w^T : M=32768, N=512, K=1024  (bf16 out)
  gemm_bt<D_MODEL, STATE_DIM, true, false>
      <<<dim3(M_TOTAL / 128, STATE_DIM / 128), 256, 0, stream>>>(
          ub, bwb, Bu, nullptr, nullptr);

  scan_chunks<<<BATCH * NCHUNK, 128, 0, stream>>>(Bu, lam, S);
  scan_carry<<<BATCH, 512, 0, stream>>>(lam, S, Hin);
  scan_final<<<BATCH * NCHUNK, 128, 0, stream>>>(Bu, lam, Hin, hb);

  // y = h @ C_w^T + D*u : M=32768, N=1024, K=512  (fp32 out, bf16 skip)
  gemm_bt<STATE_DIM, D_MODEL, false, true>
      <<<dim3(M_TOTAL / 128, D_MODEL / 128), 256, 0, stream>>>(
          hb, cwb, y, ub, Dv);
}